// Round 7
// baseline (783.754 us; speedup 1.0000x reference)
//
#include <hip/hip_runtime.h>

// Problem constants
constexpr int NTOK = 16384;   // 8*2048 tokens
constexpr int KCB  = 8192;    // codebook size
constexpr int DDIM = 128;     // dim
constexpr int OUT_MAIN = NTOK * DDIM;   // 2097152

typedef _Float16 f16x8 __attribute__((ext_vector_type(8)));
typedef _Float16 f16x2 __attribute__((ext_vector_type(2)));
typedef float    f32x4 __attribute__((ext_vector_type(4)));

constexpr float C12 = 1.0f / 4096.0f;      // 2^-12 (64*64 scale)
constexpr float C23 = 1.0f / 8388608.0f;   // 2^-23 (64*64*2048 scale)

// ---------------------------------------------------------------------------
// normalize rows of z and codebook; emit f16 hi/lo split (scaled x64) + 1/norm
// hi = f16(v*rn*64); lo = f16((vs - hi)*2048)  ->  v*rn = (hi + lo/2048)/64
// ---------------------------------------------------------------------------
__global__ __launch_bounds__(256) void norm_k(const float* __restrict__ z,
                                              const float* __restrict__ cb,
                                              _Float16* __restrict__ znh,
                                              _Float16* __restrict__ znl,
                                              _Float16* __restrict__ enh,
                                              _Float16* __restrict__ enl,
                                              float* __restrict__ zin,
                                              float* __restrict__ ein) {
  int lane = threadIdx.x & 63;
  int w    = threadIdx.x >> 6;
  int row  = blockIdx.x * 4 + w;
  const float* src;
  _Float16 *dh, *dl;
  float* nv;
  if (row < NTOK) {
    src = z + (size_t)row * DDIM;
    dh = znh + (size_t)row * DDIM;
    dl = znl + (size_t)row * DDIM;
    nv = zin + row;
  } else {
    int r = row - NTOK;
    src = cb + (size_t)r * DDIM;
    dh = enh + (size_t)r * DDIM;
    dl = enl + (size_t)r * DDIM;
    nv = ein + r;
  }
  float2 v = reinterpret_cast<const float2*>(src)[lane];
  float ss = v.x * v.x + v.y * v.y;
#pragma unroll
  for (int m = 1; m < 64; m <<= 1) ss += __shfl_xor(ss, m);
  float rn = 1.0f / fmaxf(sqrtf(ss), 1e-12f);
  if (lane == 0) *nv = rn;
  float rs = rn * 64.0f;
  float sx = v.x * rs, sy = v.y * rs;
  _Float16 hx = (_Float16)sx, hy = (_Float16)sy;
  _Float16 lx = (_Float16)((sx - (float)hx) * 2048.0f);
  _Float16 ly = (_Float16)((sy - (float)hy) * 2048.0f);
  f16x2 h2; h2.x = hx; h2.y = hy;
  f16x2 l2; l2.x = lx; l2.y = ly;
  reinterpret_cast<f16x2*>(dh)[lane] = h2;
  reinterpret_cast<f16x2*>(dl)[lane] = l2;
}

// ---------------------------------------------------------------------------
// pass1m: f16-split MFMA argmax+lse. grid (32 colparts, 16 rowparts), 256 thr.
// Wave w owns 64 codebook cols (c0 = part*256 + w*64), frags in regs (hi+lo,
// 128 VGPR, loop-invariant). Streams 64 z-row-tiles of 16 rows.
// Swapped operands: mfma(E, Z, acc) -> D col = lane&15 = z-row (lane-local
// online top2+lse, no cross-lane per score), D row = (lane>>4)*4+reg = e-col.
// ---------------------------------------------------------------------------
__global__ __launch_bounds__(256, 2) void pass1m(const _Float16* __restrict__ znh,
                                                 const _Float16* __restrict__ znl,
                                                 const _Float16* __restrict__ enh,
                                                 const _Float16* __restrict__ enl,
                                                 float* __restrict__ pb1,
                                                 int* __restrict__ pidx,
                                                 float* __restrict__ pb2,
                                                 float* __restrict__ pL) {
  __shared__ float4 mbuf[2][4][16];
  int tid = threadIdx.x, w = tid >> 6, l = tid & 63;
  int q = l >> 4, lr = l & 15;
  int part = blockIdx.x;                 // 0..31
  int c0 = part * 256 + w * 64;
  int r0 = blockIdx.y * 1024;

  f16x8 bh[4][4], bl[4][4];              // codebook frags: [coltile][kchunk]
#pragma unroll
  for (int tt = 0; tt < 4; ++tt)
#pragma unroll
    for (int dc = 0; dc < 4; ++dc) {
      int col = c0 + tt * 16 + lr;
      bh[tt][dc] = *reinterpret_cast<const f16x8*>(enh + (size_t)col * DDIM + dc * 32 + q * 8);
      bl[tt][dc] = *reinterpret_cast<const f16x8*>(enl + (size_t)col * DDIM + dc * 32 + q * 8);
    }

  for (int rt = 0; rt < 64; ++rt) {
    int zrow = r0 + rt * 16 + lr;
    f16x8 zh[4], zl[4];
#pragma unroll
    for (int dc = 0; dc < 4; ++dc) {
      zh[dc] = *reinterpret_cast<const f16x8*>(znh + (size_t)zrow * DDIM + dc * 32 + q * 8);
      zl[dc] = *reinterpret_cast<const f16x8*>(znl + (size_t)zrow * DDIM + dc * 32 + q * 8);
    }
    f32x4 hh[4], cr[4];
#pragma unroll
    for (int tt = 0; tt < 4; ++tt) {
#pragma unroll
      for (int e = 0; e < 4; ++e) { hh[tt][e] = 0.0f; cr[tt][e] = 0.0f; }
    }
#pragma unroll
    for (int dc = 0; dc < 4; ++dc)
#pragma unroll
      for (int tt = 0; tt < 4; ++tt) {
        hh[tt] = __builtin_amdgcn_mfma_f32_16x16x32_f16(bh[tt][dc], zh[dc], hh[tt], 0, 0, 0);
        cr[tt] = __builtin_amdgcn_mfma_f32_16x16x32_f16(bl[tt][dc], zh[dc], cr[tt], 0, 0, 0);
        cr[tt] = __builtin_amdgcn_mfma_f32_16x16x32_f16(bh[tt][dc], zl[dc], cr[tt], 0, 0, 0);
      }

    // per-lane online top2 + lse over 16 cols (ascending k -> first-max wins)
    float b1 = -3e38f, b2 = -3e38f, L = 0.0f;
    int b1i = 0;
#pragma unroll
    for (int tt = 0; tt < 4; ++tt)
#pragma unroll
      for (int rg = 0; rg < 4; ++rg) {
        float s = fmaf(hh[tt][rg], C12, cr[tt][rg] * C23);
        int k = c0 + tt * 16 + q * 4 + rg;
        float e = __expf((s - b1) * 10.0f);
        if (__any(s > b1)) {
          if (s > b1) {
            float en = __expf((b1 - s) * 10.0f);
            L = fmaf(L, en, 1.0f);
            b2 = b1; b1 = s; b1i = k;
          } else {
            L += e;
            b2 = fmaxf(b2, s);
          }
        } else {
          L += e;
          b2 = fmaxf(b2, s);
        }
      }
    // 2-step merge across the 4 lanes (q groups) sharing this z-row
#pragma unroll
    for (int m = 16; m <= 32; m <<= 1) {
      float ob1 = __shfl_xor(b1, m), ob2 = __shfl_xor(b2, m), oL = __shfl_xor(L, m);
      int oi = __shfl_xor(b1i, m);
      float nb = fmaxf(b1, ob1);
      L = L * __expf((b1 - nb) * 10.0f) + oL * __expf((ob1 - nb) * 10.0f);
      b2 = fmaxf(fmaxf(fminf(b1, ob1), b2), ob2);
      bool take = (ob1 > b1) || (ob1 == b1 && oi < b1i);
      if (take) b1i = oi;
      b1 = nb;
    }
    int par = rt & 1;
    if (l < 16) mbuf[par][w][l] = make_float4(b1, __int_as_float(b1i), b2, L);
    __syncthreads();
    if (w == (rt & 3) && l < 16) {        // rotate merge duty across waves
      float4 mv = mbuf[par][0][l];
      float B1 = mv.x, B2 = mv.z, LL = mv.w;
      int BI = __float_as_int(mv.y);
#pragma unroll
      for (int ww = 1; ww < 4; ++ww) {    // waves ascending = cols ascending
        float4 o = mbuf[par][ww][l];
        float ob1 = o.x, ob2 = o.z, oL = o.w;
        int oi = __float_as_int(o.y);
        float nb = fmaxf(B1, ob1);
        LL = LL * __expf((B1 - nb) * 10.0f) + oL * __expf((ob1 - nb) * 10.0f);
        B2 = fmaxf(fmaxf(fminf(B1, ob1), B2), ob2);
        if (ob1 > B1) BI = oi;
        B1 = nb;
      }
      int off = part * NTOK + r0 + rt * 16 + l;
      pb1[off] = B1; pidx[off] = BI; pb2[off] = B2; pL[off] = LL;
    }
  }
}

// ---------------------------------------------------------------------------
// merge 32 col-part partials -> lse, idx; flag near-tie rows for fp32 rescue
// ---------------------------------------------------------------------------
__global__ __launch_bounds__(256) void merge2_k(const float* __restrict__ pb1,
                                                const int* __restrict__ pidx,
                                                const float* __restrict__ pb2,
                                                const float* __restrict__ pL,
                                                float* __restrict__ lse,
                                                int* __restrict__ idxb,
                                                int* __restrict__ rcount,
                                                int* __restrict__ rlist) {
  int n = blockIdx.x * 256 + threadIdx.x;
  float B1 = pb1[n], B2 = pb2[n], LL = pL[n];
  int BI = pidx[n];
  for (int p = 1; p < 32; ++p) {
    int off = p * NTOK + n;
    float ob1 = pb1[off], ob2 = pb2[off], oL = pL[off];
    int oi = pidx[off];
    float nb = fmaxf(B1, ob1);
    LL = LL * __expf((B1 - nb) * 10.0f) + oL * __expf((ob1 - nb) * 10.0f);
    B2 = fmaxf(fmaxf(fminf(B1, ob1), B2), ob2);
    if (ob1 > B1) BI = oi;
    B1 = nb;
  }
  lse[n] = fmaf(B1, 10.0f, logf(LL));
  idxb[n] = BI;
  if (B1 - B2 < 1e-3f) {               // ~1000x the f16-split error bound
    int s = atomicAdd(rcount, 1);
    rlist[s] = n;
  }
}

// ---------------------------------------------------------------------------
// rescue: exact fp32 re-argmax for flagged rows. One block per row
// (grid-stride). Wave handles a code PAIR: lane l -> code c0+(l>>5),
// float4 at d=(l&31)*4 (coalesced 1KB per wave). 5-step butterfly reduce
// within 32-lane halves; per-lane online argmax (ascending c); 6-step
// wave merge with lower-index tie-break; LDS cross-wave merge.
// ---------------------------------------------------------------------------
__global__ __launch_bounds__(256) void rescue_k(const float* __restrict__ z,
                                                const float* __restrict__ cb,
                                                const float* __restrict__ zin,
                                                const float* __restrict__ ein,
                                                const int* __restrict__ rcount,
                                                const int* __restrict__ rlist,
                                                int* __restrict__ idxb) {
  __shared__ float rbv[4];
  __shared__ int   rbi[4];
  int tid = threadIdx.x, wv = tid >> 6, l = tid & 63;
  int half = l >> 5, ld = l & 31;
  int cnt = *rcount;
  for (int ri = blockIdx.x; ri < cnt; ri += gridDim.x) {
    int n = rlist[ri];
    __syncthreads();                     // protect rbv/rbi reuse across rows
    float rnz = zin[n];
    float4 zv = reinterpret_cast<const float4*>(z + (size_t)n * DDIM)[ld];
    zv.x *= rnz; zv.y *= rnz; zv.z *= rnz; zv.w *= rnz;
    float bv = -3e38f;
    int   bi = 0;
    for (int c0 = wv * 2; c0 < KCB; c0 += 8) {
      int c = c0 + half;
      float4 ev = reinterpret_cast<const float4*>(cb + (size_t)c * DDIM)[ld];
      float p = zv.x * ev.x;
      p = fmaf(zv.y, ev.y, p);
      p = fmaf(zv.z, ev.z, p);
      p = fmaf(zv.w, ev.w, p);
#pragma unroll
      for (int m = 1; m < 32; m <<= 1) p += __shfl_xor(p, m);
      float s = p * ein[c];
      if (s > bv) { bv = s; bi = c; }    // ascending c per lane
    }
#pragma unroll
    for (int m = 1; m < 64; m <<= 1) {
      float ov = __shfl_xor(bv, m);
      int   oi = __shfl_xor(bi, m);
      if (ov > bv || (ov == bv && oi < bi)) { bv = ov; bi = oi; }
    }
    if (l == 0) { rbv[wv] = bv; rbi[wv] = bi; }
    __syncthreads();
    if (tid == 0) {
#pragma unroll
      for (int ww = 1; ww < 4; ++ww)
        if (rbv[ww] > bv || (rbv[ww] == bv && rbi[ww] < bi)) { bv = rbv[ww]; bi = rbi[ww]; }
      idxb[n] = bi;
    }
  }
}

// ---------------------------------------------------------------------------
// counts from final idx
// ---------------------------------------------------------------------------
__global__ __launch_bounds__(256) void count_k(const int* __restrict__ idxb,
                                               int* __restrict__ counts) {
  int n = blockIdx.x * 256 + threadIdx.x;
  atomicAdd(&counts[idxb[n]], 1);
}

// ---------------------------------------------------------------------------
// pass 2 (MFMA f16-hi): recompute scores, accumulate softmax column sums.
// grid (K/64, N/128). LDS row-major f16 with 16B-chunk swizzle (G4 fix).
// scores scaled x4096 -> epilogue constant 10/4096.
// ---------------------------------------------------------------------------
__global__ __launch_bounds__(256) void pass2m(const _Float16* __restrict__ znh,
                                              const _Float16* __restrict__ enh,
                                              const float* __restrict__ lse,
                                              float* __restrict__ Ppart) {
  __shared__ _Float16 zt[128 * 128];   // 32 KB
  __shared__ _Float16 et[64 * 128];    // 16 KB
  __shared__ float colbuf[4][64];
  int tid = threadIdx.x;
  int kb = blockIdx.x, nb = blockIdx.y;
  int n0 = nb * 128, k0 = kb * 64;

#pragma unroll
  for (int p = 0; p < 8; ++p) {
    int idx = p * 256 + tid;
    int ch = idx & 15, r = idx >> 4;
    uint4 v = *reinterpret_cast<const uint4*>(znh + (size_t)(n0 + r) * DDIM + ch * 8);
    *reinterpret_cast<uint4*>(&zt[r * 128 + (ch ^ (r & 7)) * 8]) = v;
  }
#pragma unroll
  for (int p = 0; p < 4; ++p) {
    int idx = p * 256 + tid;
    int ch = idx & 15, r = idx >> 4;
    uint4 v = *reinterpret_cast<const uint4*>(enh + (size_t)(k0 + r) * DDIM + ch * 8);
    *reinterpret_cast<uint4*>(&et[r * 128 + (ch ^ (r & 7)) * 8]) = v;
  }
  __syncthreads();

  int wv = tid >> 6, l = tid & 63, lr = l & 15, lk = l >> 4;

  float lse8[2][4];
#pragma unroll
  for (int tr = 0; tr < 2; ++tr)
#pragma unroll
    for (int rg = 0; rg < 4; ++rg)
      lse8[tr][rg] = lse[n0 + wv * 32 + tr * 16 + lk * 4 + rg];

  f16x8 afr[2][4];
#pragma unroll
  for (int tr = 0; tr < 2; ++tr) {
    int row = wv * 32 + tr * 16 + lr;
#pragma unroll
    for (int dc = 0; dc < 4; ++dc)
      afr[tr][dc] = *reinterpret_cast<const f16x8*>(
          &zt[row * 128 + ((4 * dc + lk) ^ (row & 7)) * 8]);
  }

#pragma unroll
  for (int ct = 0; ct < 4; ++ct) {
    f32x4 acc0 = {0.f, 0.f, 0.f, 0.f};
    f32x4 acc1 = {0.f, 0.f, 0.f, 0.f};
    int col = ct * 16 + lr;
#pragma unroll
    for (int dc = 0; dc < 4; ++dc) {
      f16x8 bfr = *reinterpret_cast<const f16x8*>(
          &et[col * 128 + ((4 * dc + lk) ^ (col & 7)) * 8]);
      acc0 = __builtin_amdgcn_mfma_f32_16x16x32_f16(afr[0][dc], bfr, acc0, 0, 0, 0);
      acc1 = __builtin_amdgcn_mfma_f32_16x16x32_f16(afr[1][dc], bfr, acc1, 0, 0, 0);
    }
    float pc = 0.0f;
#pragma unroll
    for (int rg = 0; rg < 4; ++rg) {
      pc += __expf(fmaf(acc0[rg], 0.00244140625f, -lse8[0][rg]));   // 10/4096
      pc += __expf(fmaf(acc1[rg], 0.00244140625f, -lse8[1][rg]));
    }
    pc += __shfl_xor(pc, 16);
    pc += __shfl_xor(pc, 32);
    if (l < 16) colbuf[wv][ct * 16 + l] = pc;
  }
  __syncthreads();
  if (tid < 64)
    Ppart[(size_t)nb * KCB + k0 + tid] =
        colbuf[0][tid] + colbuf[1][tid] + colbuf[2][tid] + colbuf[3][tid];
}

// ---------------------------------------------------------------------------
// gather z_q, emit z_q_ste = z + (z_q - z), block-partial commit sums
// ---------------------------------------------------------------------------
__global__ __launch_bounds__(256) void k3(const float* __restrict__ z,
                                          const float* __restrict__ cb,
                                          const int* __restrict__ idxb,
                                          float* __restrict__ out,
                                          float* __restrict__ cpart) {
  int tid = threadIdx.x;
  int e   = blockIdx.x * 256 + tid;
  int n   = e >> 5;
  int q   = e & 31;
  int id  = idxb[n];
  float4 c4 = reinterpret_cast<const float4*>(cb)[id * 32 + q];
  float4 z4 = reinterpret_cast<const float4*>(z)[e];
  float4 o;
  o.x = z4.x + (c4.x - z4.x);
  o.y = z4.y + (c4.y - z4.y);
  o.z = z4.z + (c4.z - z4.z);
  o.w = z4.w + (c4.w - z4.w);
  reinterpret_cast<float4*>(out)[e] = o;
  float dx = c4.x - z4.x, dy = c4.y - z4.y, dz = c4.z - z4.z, dw = c4.w - z4.w;
  float ds = dx * dx + dy * dy + dz * dz + dw * dw;
#pragma unroll
  for (int m = 1; m < 64; m <<= 1) ds += __shfl_xor(ds, m);
  __shared__ float wsum[4];
  if ((tid & 63) == 0) wsum[tid >> 6] = ds;
  __syncthreads();
  if (tid == 0) cpart[blockIdx.x] = wsum[0] + wsum[1] + wsum[2] + wsum[3];
}

// ---------------------------------------------------------------------------
// reduce Ppart[rows][K] -> Psum[K]
// ---------------------------------------------------------------------------
__global__ __launch_bounds__(256) void reduceP(const float* __restrict__ Ppart,
                                               float* __restrict__ Psum,
                                               int rows) {
  int k = blockIdx.x * 256 + threadIdx.x;
  float s = 0.0f;
  for (int b = 0; b < rows; ++b) s += Ppart[(size_t)b * KCB + k];
  Psum[k] = s;
}

// ---------------------------------------------------------------------------
// final scalars: commit, perplexity, entropy_loss, min(ema)
// ---------------------------------------------------------------------------
__global__ __launch_bounds__(256) void finalk(const int* __restrict__ counts,
                                              const float* __restrict__ Psum,
                                              const float* __restrict__ pema,
                                              const float* __restrict__ cpart,
                                              float* __restrict__ out) {
  int tid = threadIdx.x;
  float s1 = 0.0f, s2 = 0.0f, cs = 0.0f, mn = 1e30f;
  const float invN = 1.0f / (float)NTOK;
  const float thr  = 0.0125f / (float)KCB;
  const float invK = 1.0f / (float)KCB;
  for (int k = tid; k < KCB; k += 256) {
    float e = (float)counts[k] * invN;
    s1 += e * logf(e + 1e-8f);
    float pa = Psum[k] * invN + 1e-8f;
    s2 += pa * logf(pa);
    float ema  = 0.9f * pema[k] + 0.1f * e;
    float emaf = (ema < thr) ? invK : ema;
    mn = fminf(mn, emaf);
  }
  for (int b = tid; b < 2048; b += 256) cs += cpart[b];
#pragma unroll
  for (int m = 1; m < 64; m <<= 1) {
    s1 += __shfl_xor(s1, m);
    s2 += __shfl_xor(s2, m);
    cs += __shfl_xor(cs, m);
    mn = fminf(mn, __shfl_xor(mn, m));
  }
  __shared__ float r1[4], r2[4], r3[4], r4[4];
  if ((tid & 63) == 0) {
    int w = tid >> 6;
    r1[w] = s1; r2[w] = s2; r3[w] = cs; r4[w] = mn;
  }
  __syncthreads();
  if (tid == 0) {
    float S1 = r1[0] + r1[1] + r1[2] + r1[3];
    float S2 = r2[0] + r2[1] + r2[2] + r2[3];
    float CS = r3[0] + r3[1] + r3[2] + r3[3];
    float MN = fminf(fminf(r4[0], r4[1]), fminf(r4[2], r4[3]));
    out[OUT_MAIN + 0] = 1.25f * CS / (float)OUT_MAIN;
    out[OUT_MAIN + 1] = expf(-S1);
    out[OUT_MAIN + 2] = -S2;
    out[OUT_MAIN + 3] = MN;
  }
}

// ---------------------------------------------------------------------------
extern "C" void kernel_launch(void* const* d_in, const int* in_sizes, int n_in,
                              void* d_out, int out_size, void* d_ws, size_t ws_size,
                              hipStream_t stream) {
  const float* z    = (const float*)d_in[0];
  const float* cb   = (const float*)d_in[1];
  const float* pema = (const float*)d_in[2];
  float* out = (float*)d_out;
  char*  ws  = (char*)d_ws;

  // workspace layout (21 MB total; Ppart aliases partials, dead after merge2)
  _Float16* znh = (_Float16*)(ws + 0x000000);            // 4 MB
  _Float16* znl = (_Float16*)(ws + 0x400000);            // 4 MB
  _Float16* enh = (_Float16*)(ws + 0x800000);            // 2 MB
  _Float16* enl = (_Float16*)(ws + 0xA00000);            // 2 MB
  char* sb = ws + 0xC00000;
  float* zin    = (float*)(sb + 0x00000);                // 64 KB
  float* ein    = (float*)(sb + 0x10000);                // 32 KB
  float* lse    = (float*)(sb + 0x18000);                // 64 KB
  int*   idxb   = (int*)  (sb + 0x28000);                // 64 KB
  int*   counts = (int*)  (sb + 0x38000);                // 32 KB
  int*   rcount = (int*)  (sb + 0x40000);                // 4 B (+pad)
  int*   rlist  = (int*)  (sb + 0x41000);                // 64 KB
  float* Psum   = (float*)(sb + 0x51000);                // 32 KB
  float* cpart  = (float*)(sb + 0x59000);                // 8 KB
  char* pb = ws + 0xD00000;                              // partials: 8 MB
  float* pb1  = (float*)(pb + 0x000000);
  int*   pidx = (int*)  (pb + 0x200000);
  float* pb2  = (float*)(pb + 0x400000);
  float* pL   = (float*)(pb + 0x600000);
  float* Ppart = (float*)(ws + 0xD00000);                // 4 MB alias (after merge2)

  hipMemsetAsync(counts, 0, KCB * sizeof(int) + 0x400, stream);  // counts + rcount

  norm_k <<<(NTOK + KCB) / 4, 256, 0, stream>>>(z, cb, znh, znl, enh, enl, zin, ein);
  pass1m <<<dim3(32, 16),     256, 0, stream>>>(znh, znl, enh, enl, pb1, pidx, pb2, pL);
  merge2_k<<<NTOK / 256,      256, 0, stream>>>(pb1, pidx, pb2, pL, lse, idxb, rcount, rlist);
  rescue_k<<<1024,            256, 0, stream>>>(z, cb, zin, ein, rcount, rlist, idxb);
  count_k<<<NTOK / 256,       256, 0, stream>>>(idxb, counts);
  pass2m <<<dim3(KCB / 64, NTOK / 128), 256, 0, stream>>>(znh, enh, lse, Ppart);
  k3     <<<NTOK * DDIM / 4 / 256, 256, 0, stream>>>(z, cb, idxb, out, cpart);
  reduceP<<<KCB / 256,        256, 0, stream>>>(Ppart, Psum, NTOK / 128);
  finalk <<<1,                256, 0, stream>>>(counts, Psum, pema, cpart, out);
}

// Round 9
// 467.550 us; speedup vs baseline: 1.6763x; 1.6763x over previous
//
#include <hip/hip_runtime.h>

// Problem constants
constexpr int NTOK = 16384;   // 8*2048 tokens
constexpr int KCB  = 8192;    // codebook size
constexpr int DDIM = 128;     // dim
constexpr int OUT_MAIN = NTOK * DDIM;   // 2097152

typedef _Float16 f16x8 __attribute__((ext_vector_type(8)));
typedef _Float16 f16x2 __attribute__((ext_vector_type(2)));
typedef float    f32x4 __attribute__((ext_vector_type(4)));

constexpr float C12 = 1.0f / 4096.0f;      // 2^-12 (64*64 scale)
constexpr float C23 = 1.0f / 8388608.0f;   // 2^-23 (64*64*2048 scale)

// ---------------------------------------------------------------------------
// normalize rows of z and codebook; emit f16 hi/lo split (scaled x64) + 1/norm
// ---------------------------------------------------------------------------
__global__ __launch_bounds__(256) void norm_k(const float* __restrict__ z,
                                              const float* __restrict__ cb,
                                              _Float16* __restrict__ znh,
                                              _Float16* __restrict__ znl,
                                              _Float16* __restrict__ enh,
                                              _Float16* __restrict__ enl,
                                              float* __restrict__ zin,
                                              float* __restrict__ ein) {
  int lane = threadIdx.x & 63;
  int w    = threadIdx.x >> 6;
  int row  = blockIdx.x * 4 + w;
  const float* src;
  _Float16 *dh, *dl;
  float* nv;
  if (row < NTOK) {
    src = z + (size_t)row * DDIM;
    dh = znh + (size_t)row * DDIM;
    dl = znl + (size_t)row * DDIM;
    nv = zin + row;
  } else {
    int r = row - NTOK;
    src = cb + (size_t)r * DDIM;
    dh = enh + (size_t)r * DDIM;
    dl = enl + (size_t)r * DDIM;
    nv = ein + r;
  }
  float2 v = reinterpret_cast<const float2*>(src)[lane];
  float ss = v.x * v.x + v.y * v.y;
#pragma unroll
  for (int m = 1; m < 64; m <<= 1) ss += __shfl_xor(ss, m);
  float rn = 1.0f / fmaxf(sqrtf(ss), 1e-12f);
  if (lane == 0) *nv = rn;
  float rs = rn * 64.0f;
  float sx = v.x * rs, sy = v.y * rs;
  _Float16 hx = (_Float16)sx, hy = (_Float16)sy;
  _Float16 lx = (_Float16)((sx - (float)hx) * 2048.0f);
  _Float16 ly = (_Float16)((sy - (float)hy) * 2048.0f);
  f16x2 h2; h2.x = hx; h2.y = hy;
  f16x2 l2; l2.x = lx; l2.y = ly;
  reinterpret_cast<f16x2*>(dh)[lane] = h2;
  reinterpret_cast<f16x2*>(dl)[lane] = l2;
}

// ---------------------------------------------------------------------------
// transpose codebook: cbT[d][k] = cb[k][d]  (LDS-tiled, coalesced both sides)
// ---------------------------------------------------------------------------
__global__ __launch_bounds__(256) void transp_k(const float* __restrict__ cb,
                                                float* __restrict__ cbT) {
  __shared__ float t[32][65];
  int tid = threadIdx.x;
  int k0 = blockIdx.x * 64, d0 = blockIdx.y * 32;
#pragma unroll
  for (int p = 0; p < 8; ++p) {
    int idx = p * 256 + tid;
    int r = idx >> 5, c = idx & 31;
    t[c][r] = cb[(size_t)(k0 + r) * DDIM + d0 + c];
  }
  __syncthreads();
#pragma unroll
  for (int p = 0; p < 8; ++p) {
    int idx = p * 256 + tid;
    int c = idx >> 6, r = idx & 63;
    cbT[(size_t)(d0 + c) * KCB + k0 + r] = t[c][r];
  }
}

// ---------------------------------------------------------------------------
// pass1m: f16-split MFMA argmax+lse. grid (32 colparts, 16 rowparts), 256 thr.
// ---------------------------------------------------------------------------
__global__ __launch_bounds__(256, 2) void pass1m(const _Float16* __restrict__ znh,
                                                 const _Float16* __restrict__ znl,
                                                 const _Float16* __restrict__ enh,
                                                 const _Float16* __restrict__ enl,
                                                 float* __restrict__ pb1,
                                                 int* __restrict__ pidx,
                                                 float* __restrict__ pb2,
                                                 float* __restrict__ pL) {
  __shared__ float4 mbuf[2][4][16];
  int tid = threadIdx.x, w = tid >> 6, l = tid & 63;
  int q = l >> 4, lr = l & 15;
  int part = blockIdx.x;                 // 0..31
  int c0 = part * 256 + w * 64;
  int r0 = blockIdx.y * 1024;

  f16x8 bh[4][4], bl[4][4];              // codebook frags: [coltile][kchunk]
#pragma unroll
  for (int tt = 0; tt < 4; ++tt)
#pragma unroll
    for (int dc = 0; dc < 4; ++dc) {
      int col = c0 + tt * 16 + lr;
      bh[tt][dc] = *reinterpret_cast<const f16x8*>(enh + (size_t)col * DDIM + dc * 32 + q * 8);
      bl[tt][dc] = *reinterpret_cast<const f16x8*>(enl + (size_t)col * DDIM + dc * 32 + q * 8);
    }

  for (int rt = 0; rt < 64; ++rt) {
    int zrow = r0 + rt * 16 + lr;
    f16x8 zh[4], zl[4];
#pragma unroll
    for (int dc = 0; dc < 4; ++dc) {
      zh[dc] = *reinterpret_cast<const f16x8*>(znh + (size_t)zrow * DDIM + dc * 32 + q * 8);
      zl[dc] = *reinterpret_cast<const f16x8*>(znl + (size_t)zrow * DDIM + dc * 32 + q * 8);
    }
    f32x4 hh[4], cr[4];
#pragma unroll
    for (int tt = 0; tt < 4; ++tt) {
#pragma unroll
      for (int e = 0; e < 4; ++e) { hh[tt][e] = 0.0f; cr[tt][e] = 0.0f; }
    }
#pragma unroll
    for (int dc = 0; dc < 4; ++dc)
#pragma unroll
      for (int tt = 0; tt < 4; ++tt) {
        hh[tt] = __builtin_amdgcn_mfma_f32_16x16x32_f16(bh[tt][dc], zh[dc], hh[tt], 0, 0, 0);
        cr[tt] = __builtin_amdgcn_mfma_f32_16x16x32_f16(bl[tt][dc], zh[dc], cr[tt], 0, 0, 0);
        cr[tt] = __builtin_amdgcn_mfma_f32_16x16x32_f16(bh[tt][dc], zl[dc], cr[tt], 0, 0, 0);
      }

    // per-lane online top2 + lse over 16 cols (ascending k -> first-max wins)
    float b1 = -3e38f, b2 = -3e38f, L = 0.0f;
    int b1i = 0;
#pragma unroll
    for (int tt = 0; tt < 4; ++tt)
#pragma unroll
      for (int rg = 0; rg < 4; ++rg) {
        float s = fmaf(hh[tt][rg], C12, cr[tt][rg] * C23);
        int k = c0 + tt * 16 + q * 4 + rg;
        float e = __expf((s - b1) * 10.0f);
        if (__any(s > b1)) {
          if (s > b1) {
            float en = __expf((b1 - s) * 10.0f);
            L = fmaf(L, en, 1.0f);
            b2 = b1; b1 = s; b1i = k;
          } else {
            L += e;
            b2 = fmaxf(b2, s);
          }
        } else {
          L += e;
          b2 = fmaxf(b2, s);
        }
      }
    // 2-step merge across the 4 lanes (q groups) sharing this z-row
#pragma unroll
    for (int m = 16; m <= 32; m <<= 1) {
      float ob1 = __shfl_xor(b1, m), ob2 = __shfl_xor(b2, m), oL = __shfl_xor(L, m);
      int oi = __shfl_xor(b1i, m);
      float nb = fmaxf(b1, ob1);
      L = L * __expf((b1 - nb) * 10.0f) + oL * __expf((ob1 - nb) * 10.0f);
      b2 = fmaxf(fmaxf(fminf(b1, ob1), b2), ob2);
      bool take = (ob1 > b1) || (ob1 == b1 && oi < b1i);
      if (take) b1i = oi;
      b1 = nb;
    }
    int par = rt & 1;
    if (l < 16) mbuf[par][w][l] = make_float4(b1, __int_as_float(b1i), b2, L);
    __syncthreads();
    if (w == (rt & 3) && l < 16) {        // rotate merge duty across waves
      float4 mv = mbuf[par][0][l];
      float B1 = mv.x, B2 = mv.z, LL = mv.w;
      int BI = __float_as_int(mv.y);
#pragma unroll
      for (int ww = 1; ww < 4; ++ww) {    // waves ascending = cols ascending
        float4 o = mbuf[par][ww][l];
        float ob1 = o.x, ob2 = o.z, oL = o.w;
        int oi = __float_as_int(o.y);
        float nb = fmaxf(B1, ob1);
        LL = LL * __expf((B1 - nb) * 10.0f) + oL * __expf((ob1 - nb) * 10.0f);
        B2 = fmaxf(fmaxf(fminf(B1, ob1), B2), ob2);
        if (ob1 > B1) BI = oi;
        B1 = nb;
      }
      int off = part * NTOK + r0 + rt * 16 + l;
      pb1[off] = B1; pidx[off] = BI; pb2[off] = B2; pL[off] = LL;
    }
  }
}

// ---------------------------------------------------------------------------
// merge 32 col-part partials -> lse, idx; flag near-tie rows for fp32 rescue
// ---------------------------------------------------------------------------
__global__ __launch_bounds__(256) void merge2_k(const float* __restrict__ pb1,
                                                const int* __restrict__ pidx,
                                                const float* __restrict__ pb2,
                                                const float* __restrict__ pL,
                                                float* __restrict__ lse,
                                                int* __restrict__ idxb,
                                                int* __restrict__ rcount,
                                                int* __restrict__ rlist) {
  int n = blockIdx.x * 256 + threadIdx.x;
  float B1 = pb1[n], B2 = pb2[n], LL = pL[n];
  int BI = pidx[n];
  for (int p = 1; p < 32; ++p) {
    int off = p * NTOK + n;
    float ob1 = pb1[off], ob2 = pb2[off], oL = pL[off];
    int oi = pidx[off];
    float nb = fmaxf(B1, ob1);
    LL = LL * __expf((B1 - nb) * 10.0f) + oL * __expf((ob1 - nb) * 10.0f);
    B2 = fmaxf(fmaxf(fminf(B1, ob1), B2), ob2);
    if (ob1 > B1) BI = oi;
    B1 = nb;
  }
  lse[n] = fmaf(B1, 10.0f, logf(LL));
  idxb[n] = BI;
  if (B1 - B2 < 2e-4f) {               // ~600x the f16-split error bound
    int s = atomicAdd(rcount, 1);
    rlist[s] = n;
  }
}

// ---------------------------------------------------------------------------
// rescue2: exact fp32 re-argmax via TRANSPOSED codebook. Block per flagged
// row (grid-stride); coalesced cbT loads; no cross-lane ops per score.
// ---------------------------------------------------------------------------
__global__ __launch_bounds__(256) void rescue2_k(const float* __restrict__ z,
                                                 const float* __restrict__ cbT,
                                                 const float* __restrict__ zin,
                                                 const float* __restrict__ ein,
                                                 const int* __restrict__ rcount,
                                                 const int* __restrict__ rlist,
                                                 int* __restrict__ idxb) {
  __shared__ float zr[DDIM];
  __shared__ float rbv[4];
  __shared__ int   rbi[4];
  int tid = threadIdx.x;
  int cnt = *rcount;
  for (int ri = blockIdx.x; ri < cnt; ri += gridDim.x) {
    int n = rlist[ri];
    __syncthreads();                     // protect zr/rbv reuse across rows
    if (tid < 32) {
      float rnz = zin[n];
      float4 v = reinterpret_cast<const float4*>(z + (size_t)n * DDIM)[tid];
      v.x *= rnz; v.y *= rnz; v.z *= rnz; v.w *= rnz;
      reinterpret_cast<float4*>(zr)[tid] = v;
    }
    __syncthreads();
    float bv = -3e38f;
    int   bi = 0;
#pragma unroll
    for (int ch = 0; ch < 8; ++ch) {
      int c0 = ch * 1024 + tid * 4;
      float4 acc = make_float4(0.f, 0.f, 0.f, 0.f);
#pragma unroll 4
      for (int d = 0; d < DDIM; ++d) {
        float4 e = reinterpret_cast<const float4*>(cbT + (size_t)d * KCB)[ch * 256 + tid];
        float zd = zr[d];
        acc.x = fmaf(e.x, zd, acc.x);
        acc.y = fmaf(e.y, zd, acc.y);
        acc.z = fmaf(e.z, zd, acc.z);
        acc.w = fmaf(e.w, zd, acc.w);
      }
      float4 ev = reinterpret_cast<const float4*>(ein)[ch * 256 + tid];
      float s0 = acc.x * ev.x, s1 = acc.y * ev.y, s2 = acc.z * ev.z, s3 = acc.w * ev.w;
      if (s0 > bv) { bv = s0; bi = c0; }
      if (s1 > bv) { bv = s1; bi = c0 + 1; }
      if (s2 > bv) { bv = s2; bi = c0 + 2; }
      if (s3 > bv) { bv = s3; bi = c0 + 3; }
    }
#pragma unroll
    for (int m = 1; m < 64; m <<= 1) {
      float ov = __shfl_xor(bv, m);
      int   oi = __shfl_xor(bi, m);
      if (ov > bv || (ov == bv && oi < bi)) { bv = ov; bi = oi; }
    }
    int wv = tid >> 6;
    if ((tid & 63) == 0) { rbv[wv] = bv; rbi[wv] = bi; }
    __syncthreads();
    if (tid == 0) {
#pragma unroll
      for (int ww = 1; ww < 4; ++ww)
        if (rbv[ww] > bv || (rbv[ww] == bv && rbi[ww] < bi)) { bv = rbv[ww]; bi = rbi[ww]; }
      idxb[n] = bi;
    }
  }
}

// ---------------------------------------------------------------------------
// rescue (fallback, no cbT space): R7 design
// ---------------------------------------------------------------------------
__global__ __launch_bounds__(256) void rescue_k(const float* __restrict__ z,
                                                const float* __restrict__ cb,
                                                const float* __restrict__ zin,
                                                const float* __restrict__ ein,
                                                const int* __restrict__ rcount,
                                                const int* __restrict__ rlist,
                                                int* __restrict__ idxb) {
  __shared__ float rbv[4];
  __shared__ int   rbi[4];
  int tid = threadIdx.x, wv = tid >> 6, l = tid & 63;
  int half = l >> 5, ld = l & 31;
  int cnt = *rcount;
  for (int ri = blockIdx.x; ri < cnt; ri += gridDim.x) {
    int n = rlist[ri];
    __syncthreads();
    float rnz = zin[n];
    float4 zv = reinterpret_cast<const float4*>(z + (size_t)n * DDIM)[ld];
    zv.x *= rnz; zv.y *= rnz; zv.z *= rnz; zv.w *= rnz;
    float bv = -3e38f;
    int   bi = 0;
    for (int c0 = wv * 2; c0 < KCB; c0 += 8) {
      int c = c0 + half;
      float4 ev = reinterpret_cast<const float4*>(cb + (size_t)c * DDIM)[ld];
      float p = zv.x * ev.x;
      p = fmaf(zv.y, ev.y, p);
      p = fmaf(zv.z, ev.z, p);
      p = fmaf(zv.w, ev.w, p);
#pragma unroll
      for (int m = 1; m < 32; m <<= 1) p += __shfl_xor(p, m);
      float s = p * ein[c];
      if (s > bv) { bv = s; bi = c; }
    }
#pragma unroll
    for (int m = 1; m < 64; m <<= 1) {
      float ov = __shfl_xor(bv, m);
      int   oi = __shfl_xor(bi, m);
      if (ov > bv || (ov == bv && oi < bi)) { bv = ov; bi = oi; }
    }
    if (l == 0) { rbv[wv] = bv; rbi[wv] = bi; }
    __syncthreads();
    if (tid == 0) {
#pragma unroll
      for (int ww = 1; ww < 4; ++ww)
        if (rbv[ww] > bv || (rbv[ww] == bv && rbi[ww] < bi)) { bv = rbv[ww]; bi = rbi[ww]; }
      idxb[n] = bi;
    }
  }
}

// ---------------------------------------------------------------------------
// counts from final idx
// ---------------------------------------------------------------------------
__global__ __launch_bounds__(256) void count_k(const int* __restrict__ idxb,
                                               int* __restrict__ counts) {
  int n = blockIdx.x * 256 + threadIdx.x;
  atomicAdd(&counts[idxb[n]], 1);
}

// ---------------------------------------------------------------------------
// pass 2 (MFMA f16-hi): recompute scores, accumulate softmax column sums.
// ---------------------------------------------------------------------------
__global__ __launch_bounds__(256) void pass2m(const _Float16* __restrict__ znh,
                                              const _Float16* __restrict__ enh,
                                              const float* __restrict__ lse,
                                              float* __restrict__ Ppart) {
  __shared__ _Float16 zt[128 * 128];   // 32 KB
  __shared__ _Float16 et[64 * 128];    // 16 KB
  __shared__ float colbuf[4][64];
  int tid = threadIdx.x;
  int kb = blockIdx.x, nb = blockIdx.y;
  int n0 = nb * 128, k0 = kb * 64;

#pragma unroll
  for (int p = 0; p < 8; ++p) {
    int idx = p * 256 + tid;
    int ch = idx & 15, r = idx >> 4;
    uint4 v = *reinterpret_cast<const uint4*>(znh + (size_t)(n0 + r) * DDIM + ch * 8);
    *reinterpret_cast<uint4*>(&zt[r * 128 + (ch ^ (r & 7)) * 8]) = v;
  }
#pragma unroll
  for (int p = 0; p < 4; ++p) {
    int idx = p * 256 + tid;
    int ch = idx & 15, r = idx >> 4;
    uint4 v = *reinterpret_cast<const uint4*>(enh + (size_t)(k0 + r) * DDIM + ch * 8);
    *reinterpret_cast<uint4*>(&et[r * 128 + (ch ^ (r & 7)) * 8]) = v;
  }
  __syncthreads();

  int wv = tid >> 6, l = tid & 63, lr = l & 15, lk = l >> 4;

  float lse8[2][4];
#pragma unroll
  for (int tr = 0; tr < 2; ++tr)
#pragma unroll
    for (int rg = 0; rg < 4; ++rg)
      lse8[tr][rg] = lse[n0 + wv * 32 + tr * 16 + lk * 4 + rg];

  f16x8 afr[2][4];
#pragma unroll
  for (int tr = 0; tr < 2; ++tr) {
    int row = wv * 32 + tr * 16 + lr;
#pragma unroll
    for (int dc = 0; dc < 4; ++dc)
      afr[tr][dc] = *reinterpret_cast<const f16x8*>(
          &zt[row * 128 + ((4 * dc + lk) ^ (row & 7)) * 8]);
  }

#pragma unroll
  for (int ct = 0; ct < 4; ++ct) {
    f32x4 acc0 = {0.f, 0.f, 0.f, 0.f};
    f32x4 acc1 = {0.f, 0.f, 0.f, 0.f};
    int col = ct * 16 + lr;
#pragma unroll
    for (int dc = 0; dc < 4; ++dc) {
      f16x8 bfr = *reinterpret_cast<const f16x8*>(
          &et[col * 128 + ((4 * dc + lk) ^ (col & 7)) * 8]);
      acc0 = __builtin_amdgcn_mfma_f32_16x16x32_f16(afr[0][dc], bfr, acc0, 0, 0, 0);
      acc1 = __builtin_amdgcn_mfma_f32_16x16x32_f16(afr[1][dc], bfr, acc1, 0, 0, 0);
    }
    float pc = 0.0f;
#pragma unroll
    for (int rg = 0; rg < 4; ++rg) {
      pc += __expf(fmaf(acc0[rg], 0.00244140625f, -lse8[0][rg]));   // 10/4096
      pc += __expf(fmaf(acc1[rg], 0.00244140625f, -lse8[1][rg]));
    }
    pc += __shfl_xor(pc, 16);
    pc += __shfl_xor(pc, 32);
    if (l < 16) colbuf[wv][ct * 16 + l] = pc;
  }
  __syncthreads();
  if (tid < 64)
    Ppart[(size_t)nb * KCB + k0 + tid] =
        colbuf[0][tid] + colbuf[1][tid] + colbuf[2][tid] + colbuf[3][tid];
}

// ---------------------------------------------------------------------------
// gather z_q, emit z_q_ste = z + (z_q - z), block-partial commit sums
// ---------------------------------------------------------------------------
__global__ __launch_bounds__(256) void k3(const float* __restrict__ z,
                                          const float* __restrict__ cb,
                                          const int* __restrict__ idxb,
                                          float* __restrict__ out,
                                          float* __restrict__ cpart) {
  int tid = threadIdx.x;
  int e   = blockIdx.x * 256 + tid;
  int n   = e >> 5;
  int q   = e & 31;
  int id  = idxb[n];
  float4 c4 = reinterpret_cast<const float4*>(cb)[id * 32 + q];
  float4 z4 = reinterpret_cast<const float4*>(z)[e];
  float4 o;
  o.x = z4.x + (c4.x - z4.x);
  o.y = z4.y + (c4.y - z4.y);
  o.z = z4.z + (c4.z - z4.z);
  o.w = z4.w + (c4.w - z4.w);
  reinterpret_cast<float4*>(out)[e] = o;
  float dx = c4.x - z4.x, dy = c4.y - z4.y, dz = c4.z - z4.z, dw = c4.w - z4.w;
  float ds = dx * dx + dy * dy + dz * dz + dw * dw;
#pragma unroll
  for (int m = 1; m < 64; m <<= 1) ds += __shfl_xor(ds, m);
  __shared__ float wsum[4];
  if ((tid & 63) == 0) wsum[tid >> 6] = ds;
  __syncthreads();
  if (tid == 0) cpart[blockIdx.x] = wsum[0] + wsum[1] + wsum[2] + wsum[3];
}

// ---------------------------------------------------------------------------
// reduce Ppart[rows][K] -> Psum[K]
// ---------------------------------------------------------------------------
__global__ __launch_bounds__(256) void reduceP(const float* __restrict__ Ppart,
                                               float* __restrict__ Psum,
                                               int rows) {
  int k = blockIdx.x * 256 + threadIdx.x;
  float s = 0.0f;
  for (int b = 0; b < rows; ++b) s += Ppart[(size_t)b * KCB + k];
  Psum[k] = s;
}

// ---------------------------------------------------------------------------
// final scalars: commit, perplexity, entropy_loss, min(ema)
// ---------------------------------------------------------------------------
__global__ __launch_bounds__(256) void finalk(const int* __restrict__ counts,
                                              const float* __restrict__ Psum,
                                              const float* __restrict__ pema,
                                              const float* __restrict__ cpart,
                                              float* __restrict__ out) {
  int tid = threadIdx.x;
  float s1 = 0.0f, s2 = 0.0f, cs = 0.0f, mn = 1e30f;
  const float invN = 1.0f / (float)NTOK;
  const float thr  = 0.0125f / (float)KCB;
  const float invK = 1.0f / (float)KCB;
  for (int k = tid; k < KCB; k += 256) {
    float e = (float)counts[k] * invN;
    s1 += e * logf(e + 1e-8f);
    float pa = Psum[k] * invN + 1e-8f;
    s2 += pa * logf(pa);
    float ema  = 0.9f * pema[k] + 0.1f * e;
    float emaf = (ema < thr) ? invK : ema;
    mn = fminf(mn, emaf);
  }
  for (int b = tid; b < 2048; b += 256) cs += cpart[b];
#pragma unroll
  for (int m = 1; m < 64; m <<= 1) {
    s1 += __shfl_xor(s1, m);
    s2 += __shfl_xor(s2, m);
    cs += __shfl_xor(cs, m);
    mn = fminf(mn, __shfl_xor(mn, m));
  }
  __shared__ float r1[4], r2[4], r3[4], r4[4];
  if ((tid & 63) == 0) {
    int w = tid >> 6;
    r1[w] = s1; r2[w] = s2; r3[w] = cs; r4[w] = mn;
  }
  __syncthreads();
  if (tid == 0) {
    float S1 = r1[0] + r1[1] + r1[2] + r1[3];
    float S2 = r2[0] + r2[1] + r2[2] + r2[3];
    float CS = r3[0] + r3[1] + r3[2] + r3[3];
    float MN = fminf(fminf(r4[0], r4[1]), fminf(r4[2], r4[3]));
    out[OUT_MAIN + 0] = 1.25f * CS / (float)OUT_MAIN;
    out[OUT_MAIN + 1] = expf(-S1);
    out[OUT_MAIN + 2] = -S2;
    out[OUT_MAIN + 3] = MN;
  }
}

// ---------------------------------------------------------------------------
extern "C" void kernel_launch(void* const* d_in, const int* in_sizes, int n_in,
                              void* d_out, int out_size, void* d_ws, size_t ws_size,
                              hipStream_t stream) {
  const float* z    = (const float*)d_in[0];
  const float* cb   = (const float*)d_in[1];
  const float* pema = (const float*)d_in[2];
  float* out = (float*)d_out;
  char*  ws  = (char*)d_ws;

  // workspace layout (25 MB with cbT; 21 MB without)
  _Float16* znh = (_Float16*)(ws + 0x000000);            // 4 MB
  _Float16* znl = (_Float16*)(ws + 0x400000);            // 4 MB
  _Float16* enh = (_Float16*)(ws + 0x800000);            // 2 MB
  _Float16* enl = (_Float16*)(ws + 0xA00000);            // 2 MB
  char* sb = ws + 0xC00000;
  float* zin    = (float*)(sb + 0x00000);                // 64 KB
  float* ein    = (float*)(sb + 0x10000);                // 32 KB
  float* lse    = (float*)(sb + 0x18000);                // 64 KB
  int*   idxb   = (int*)  (sb + 0x28000);                // 64 KB
  int*   counts = (int*)  (sb + 0x38000);                // 32 KB
  int*   rcount = (int*)  (sb + 0x40000);                // 4 B (+pad)
  int*   rlist  = (int*)  (sb + 0x41000);                // 64 KB
  float* Psum   = (float*)(sb + 0x51000);                // 32 KB
  float* cpart  = (float*)(sb + 0x59000);                // 8 KB
  char* pb = ws + 0xD00000;                              // partials: 8 MB
  float* pb1  = (float*)(pb + 0x000000);
  int*   pidx = (int*)  (pb + 0x200000);
  float* pb2  = (float*)(pb + 0x400000);
  float* pL   = (float*)(pb + 0x600000);
  float* Ppart = (float*)(ws + 0xD00000);                // 4 MB alias (after merge2)
  float* cbT   = (float*)(ws + 0x1500000);               // 4 MB (optional)

  bool havecbt = ws_size >= (size_t)0x1900000;

  hipMemsetAsync(counts, 0, KCB * sizeof(int) + 0x400, stream);  // counts + rcount

  norm_k <<<(NTOK + KCB) / 4, 256, 0, stream>>>(z, cb, znh, znl, enh, enl, zin, ein);
  if (havecbt)
    transp_k<<<dim3(KCB / 64, DDIM / 32), 256, 0, stream>>>(cb, cbT);
  pass1m <<<dim3(32, 16),     256, 0, stream>>>(znh, znl, enh, enl, pb1, pidx, pb2, pL);
  merge2_k<<<NTOK / 256,      256, 0, stream>>>(pb1, pidx, pb2, pL, lse, idxb, rcount, rlist);
  if (havecbt)
    rescue2_k<<<2048,         256, 0, stream>>>(z, cbT, zin, ein, rcount, rlist, idxb);
  else
    rescue_k<<<1024,          256, 0, stream>>>(z, cb, zin, ein, rcount, rlist, idxb);
  count_k<<<NTOK / 256,       256, 0, stream>>>(idxb, counts);
  pass2m <<<dim3(KCB / 64, NTOK / 128), 256, 0, stream>>>(znh, enh, lse, Ppart);
  k3     <<<NTOK * DDIM / 4 / 256, 256, 0, stream>>>(z, cb, idxb, out, cpart);
  reduceP<<<KCB / 256,        256, 0, stream>>>(Ppart, Psum, NTOK / 128);
  finalk <<<1,                256, 0, stream>>>(counts, Psum, pema, cpart, out);
}

// Round 10
// 412.938 us; speedup vs baseline: 1.8980x; 1.1323x over previous
//
#include <hip/hip_runtime.h>

// Problem constants
constexpr int NTOK = 16384;   // 8*2048 tokens
constexpr int KCB  = 8192;    // codebook size
constexpr int DDIM = 128;     // dim
constexpr int OUT_MAIN = NTOK * DDIM;   // 2097152

typedef _Float16 f16x8 __attribute__((ext_vector_type(8)));
typedef _Float16 f16x2 __attribute__((ext_vector_type(2)));
typedef float    f32x4 __attribute__((ext_vector_type(4)));

// exp2-logit domain: l2 = cos * 10 * log2(e). Scores from MFMA are scaled
// by 4096 (hi*hi) and 2^23 (cross), so:
constexpr float S12 = 0.0035222047f;   // 10*log2(e) / 4096
constexpr float S23 = 1.7198449e-6f;   // 10*log2(e) / 2^23
constexpr float RTHR = 2.886e-3f;      // rescue threshold (2e-4 cos) in l2

// ---------------------------------------------------------------------------
// normalize rows of z and codebook; emit f16 hi/lo split (scaled x64) + 1/norm
// ---------------------------------------------------------------------------
__global__ __launch_bounds__(256) void norm_k(const float* __restrict__ z,
                                              const float* __restrict__ cb,
                                              _Float16* __restrict__ znh,
                                              _Float16* __restrict__ znl,
                                              _Float16* __restrict__ enh,
                                              _Float16* __restrict__ enl,
                                              float* __restrict__ zin,
                                              float* __restrict__ ein) {
  int lane = threadIdx.x & 63;
  int w    = threadIdx.x >> 6;
  int row  = blockIdx.x * 4 + w;
  const float* src;
  _Float16 *dh, *dl;
  float* nv;
  if (row < NTOK) {
    src = z + (size_t)row * DDIM;
    dh = znh + (size_t)row * DDIM;
    dl = znl + (size_t)row * DDIM;
    nv = zin + row;
  } else {
    int r = row - NTOK;
    src = cb + (size_t)r * DDIM;
    dh = enh + (size_t)r * DDIM;
    dl = enl + (size_t)r * DDIM;
    nv = ein + r;
  }
  float2 v = reinterpret_cast<const float2*>(src)[lane];
  float ss = v.x * v.x + v.y * v.y;
#pragma unroll
  for (int m = 1; m < 64; m <<= 1) ss += __shfl_xor(ss, m);
  float rn = 1.0f / fmaxf(sqrtf(ss), 1e-12f);
  if (lane == 0) *nv = rn;
  float rs = rn * 64.0f;
  float sx = v.x * rs, sy = v.y * rs;
  _Float16 hx = (_Float16)sx, hy = (_Float16)sy;
  _Float16 lx = (_Float16)((sx - (float)hx) * 2048.0f);
  _Float16 ly = (_Float16)((sy - (float)hy) * 2048.0f);
  f16x2 h2; h2.x = hx; h2.y = hy;
  f16x2 l2; l2.x = lx; l2.y = ly;
  reinterpret_cast<f16x2*>(dh)[lane] = h2;
  reinterpret_cast<f16x2*>(dl)[lane] = l2;
}

// ---------------------------------------------------------------------------
// transpose codebook: cbT[d][k] = cb[k][d]  (LDS-tiled, coalesced both sides)
// ---------------------------------------------------------------------------
__global__ __launch_bounds__(256) void transp_k(const float* __restrict__ cb,
                                                float* __restrict__ cbT) {
  __shared__ float t[32][65];
  int tid = threadIdx.x;
  int k0 = blockIdx.x * 64, d0 = blockIdx.y * 32;
#pragma unroll
  for (int p = 0; p < 8; ++p) {
    int idx = p * 256 + tid;
    int r = idx >> 5, c = idx & 31;
    t[c][r] = cb[(size_t)(k0 + r) * DDIM + d0 + c];
  }
  __syncthreads();
#pragma unroll
  for (int p = 0; p < 8; ++p) {
    int idx = p * 256 + tid;
    int c = idx >> 6, r = idx & 63;
    cbT[(size_t)(d0 + c) * KCB + k0 + r] = t[c][r];
  }
}

// ---------------------------------------------------------------------------
// pass1m: f16-split MFMA argmax+lse in exp2-logit domain.
// grid (32 colparts, 32 rowparts), 256 thr. Wave w owns 64 cols; 32 row-tiles
// of 16 rows each. Branchless per-lane top2+argmax; per-rt q-shuffle merge;
// cross-wave merge DEFERRED to one LDS pass at the end (1 barrier total).
// ---------------------------------------------------------------------------
__global__ __launch_bounds__(256, 2) void pass1m(const _Float16* __restrict__ znh,
                                                 const _Float16* __restrict__ znl,
                                                 const _Float16* __restrict__ enh,
                                                 const _Float16* __restrict__ enl,
                                                 float* __restrict__ pb1,
                                                 int* __restrict__ pidx,
                                                 float* __restrict__ pb2,
                                                 float* __restrict__ pL) {
  __shared__ float4 mbuf[32][4][16];   // 32 KB: [rt][wave][row]
  int tid = threadIdx.x, w = tid >> 6, l = tid & 63;
  int q = l >> 4, lr = l & 15;
  int part = blockIdx.x;               // 0..31
  int c0 = part * 256 + w * 64;
  int r0 = blockIdx.y * 512;           // 32 rowparts

  f16x8 bh[4][4], bl[4][4];            // codebook frags: [coltile][kchunk]
#pragma unroll
  for (int tt = 0; tt < 4; ++tt)
#pragma unroll
    for (int dc = 0; dc < 4; ++dc) {
      int col = c0 + tt * 16 + lr;
      bh[tt][dc] = *reinterpret_cast<const f16x8*>(enh + (size_t)col * DDIM + dc * 32 + q * 8);
      bl[tt][dc] = *reinterpret_cast<const f16x8*>(enl + (size_t)col * DDIM + dc * 32 + q * 8);
    }

  for (int rt = 0; rt < 32; ++rt) {
    int zrow = r0 + rt * 16 + lr;
    f16x8 zh[4], zl[4];
#pragma unroll
    for (int dc = 0; dc < 4; ++dc) {
      zh[dc] = *reinterpret_cast<const f16x8*>(znh + (size_t)zrow * DDIM + dc * 32 + q * 8);
      zl[dc] = *reinterpret_cast<const f16x8*>(znl + (size_t)zrow * DDIM + dc * 32 + q * 8);
    }
    f32x4 hh[4], cr[4];
#pragma unroll
    for (int tt = 0; tt < 4; ++tt) {
#pragma unroll
      for (int e = 0; e < 4; ++e) { hh[tt][e] = 0.0f; cr[tt][e] = 0.0f; }
    }
#pragma unroll
    for (int dc = 0; dc < 4; ++dc)
#pragma unroll
      for (int tt = 0; tt < 4; ++tt) {
        hh[tt] = __builtin_amdgcn_mfma_f32_16x16x32_f16(bh[tt][dc], zh[dc], hh[tt], 0, 0, 0);
        cr[tt] = __builtin_amdgcn_mfma_f32_16x16x32_f16(bl[tt][dc], zh[dc], cr[tt], 0, 0, 0);
        cr[tt] = __builtin_amdgcn_mfma_f32_16x16x32_f16(bh[tt][dc], zl[dc], cr[tt], 0, 0, 0);
      }

    // scores in l2 domain (branchless from here on)
    float s[16];
#pragma unroll
    for (int tt = 0; tt < 4; ++tt)
#pragma unroll
      for (int rg = 0; rg < 4; ++rg)
        s[tt * 4 + rg] = fmaf(hh[tt][rg], S12, cr[tt][rg] * S23);

    // streaming top2 + argmax over 16 (i ascending = k ascending within lane)
    float m1 = s[0], m2 = -3e38f;
    int ii = 0;
#pragma unroll
    for (int i = 1; i < 16; ++i) {
      float sv = s[i];
      m2 = fmaxf(m2, fminf(sv, m1));
      ii = (sv > m1) ? i : ii;
      m1 = fmaxf(m1, sv);
    }
    float sum = 0.0f;
#pragma unroll
    for (int i = 0; i < 16; ++i) sum += exp2f(s[i] - m1);
    int kk = c0 + q * 4 + ((ii >> 2) << 4) + (ii & 3);

    // q-group merge (lanes sharing this z-row), index-aware tie-break
#pragma unroll
    for (int m = 16; m <= 32; m <<= 1) {
      float o1 = __shfl_xor(m1, m), o2 = __shfl_xor(m2, m), oS = __shfl_xor(sum, m);
      int ok = __shfl_xor(kk, m);
      float nm = fmaxf(m1, o1);
      sum = sum * exp2f(m1 - nm) + oS * exp2f(o1 - nm);
      m2 = fmaxf(fmaxf(fminf(m1, o1), m2), o2);
      if (o1 > m1 || (o1 == m1 && ok < kk)) kk = ok;
      m1 = nm;
    }
    if (l < 16) mbuf[rt][w][l] = make_float4(m1, __int_as_float(kk), m2, sum);
  }

  __syncthreads();
  int base = part * NTOK + r0;
  for (int e = tid; e < 512; e += 256) {
    int rt = e >> 4, rr = e & 15;
    float4 a = mbuf[rt][0][rr];
    float B1 = a.x, B2 = a.z, LL = a.w;
    int BI = __float_as_int(a.y);
#pragma unroll
    for (int ww = 1; ww < 4; ++ww) {   // waves ascending = col blocks ascending
      float4 o = mbuf[rt][ww][rr];
      float nb = fmaxf(B1, o.x);
      LL = LL * exp2f(B1 - nb) + o.w * exp2f(o.x - nb);
      B2 = fmaxf(fmaxf(fminf(B1, o.x), B2), o.z);
      if (o.x > B1) BI = __float_as_int(o.y);
      B1 = nb;
    }
    int n = base + rt * 16 + rr;
    pb1[n] = B1; pidx[n] = BI; pb2[n] = B2; pL[n] = LL;
  }
}

// ---------------------------------------------------------------------------
// merge 32 col-part partials -> lse (log2 domain), idx; flag near-ties
// ---------------------------------------------------------------------------
__global__ __launch_bounds__(256) void merge2_k(const float* __restrict__ pb1,
                                                const int* __restrict__ pidx,
                                                const float* __restrict__ pb2,
                                                const float* __restrict__ pL,
                                                float* __restrict__ lse,
                                                int* __restrict__ idxb,
                                                int* __restrict__ rcount,
                                                int* __restrict__ rlist) {
  int n = blockIdx.x * 256 + threadIdx.x;
  float B1 = pb1[n], B2 = pb2[n], LL = pL[n];
  int BI = pidx[n];
  for (int p = 1; p < 32; ++p) {
    int off = p * NTOK + n;
    float ob1 = pb1[off], ob2 = pb2[off], oL = pL[off];
    int oi = pidx[off];
    float nb = fmaxf(B1, ob1);
    LL = LL * exp2f(B1 - nb) + oL * exp2f(ob1 - nb);
    B2 = fmaxf(fmaxf(fminf(B1, ob1), B2), ob2);
    if (ob1 > B1) BI = oi;
    B1 = nb;
  }
  lse[n] = B1 + __log2f(LL);           // log2-domain lse
  idxb[n] = BI;
  if (B1 - B2 < RTHR) {
    int s = atomicAdd(rcount, 1);
    rlist[s] = n;
  }
}

// ---------------------------------------------------------------------------
// rescue2: exact fp32 re-argmax via TRANSPOSED codebook (coalesced, no
// cross-lane ops per score).
// ---------------------------------------------------------------------------
__global__ __launch_bounds__(256) void rescue2_k(const float* __restrict__ z,
                                                 const float* __restrict__ cbT,
                                                 const float* __restrict__ zin,
                                                 const float* __restrict__ ein,
                                                 const int* __restrict__ rcount,
                                                 const int* __restrict__ rlist,
                                                 int* __restrict__ idxb) {
  __shared__ float zr[DDIM];
  __shared__ float rbv[4];
  __shared__ int   rbi[4];
  int tid = threadIdx.x;
  int cnt = *rcount;
  for (int ri = blockIdx.x; ri < cnt; ri += gridDim.x) {
    int n = rlist[ri];
    __syncthreads();                     // protect zr/rbv reuse across rows
    if (tid < 32) {
      float rnz = zin[n];
      float4 v = reinterpret_cast<const float4*>(z + (size_t)n * DDIM)[tid];
      v.x *= rnz; v.y *= rnz; v.z *= rnz; v.w *= rnz;
      reinterpret_cast<float4*>(zr)[tid] = v;
    }
    __syncthreads();
    float bv = -3e38f;
    int   bi = 0;
#pragma unroll
    for (int ch = 0; ch < 8; ++ch) {
      int c0 = ch * 1024 + tid * 4;
      float4 acc = make_float4(0.f, 0.f, 0.f, 0.f);
#pragma unroll 4
      for (int d = 0; d < DDIM; ++d) {
        float4 e = reinterpret_cast<const float4*>(cbT + (size_t)d * KCB)[ch * 256 + tid];
        float zd = zr[d];
        acc.x = fmaf(e.x, zd, acc.x);
        acc.y = fmaf(e.y, zd, acc.y);
        acc.z = fmaf(e.z, zd, acc.z);
        acc.w = fmaf(e.w, zd, acc.w);
      }
      float4 ev = reinterpret_cast<const float4*>(ein)[ch * 256 + tid];
      float s0 = acc.x * ev.x, s1 = acc.y * ev.y, s2 = acc.z * ev.z, s3 = acc.w * ev.w;
      if (s0 > bv) { bv = s0; bi = c0; }
      if (s1 > bv) { bv = s1; bi = c0 + 1; }
      if (s2 > bv) { bv = s2; bi = c0 + 2; }
      if (s3 > bv) { bv = s3; bi = c0 + 3; }
    }
#pragma unroll
    for (int m = 1; m < 64; m <<= 1) {
      float ov = __shfl_xor(bv, m);
      int   oi = __shfl_xor(bi, m);
      if (ov > bv || (ov == bv && oi < bi)) { bv = ov; bi = oi; }
    }
    int wv = tid >> 6;
    if ((tid & 63) == 0) { rbv[wv] = bv; rbi[wv] = bi; }
    __syncthreads();
    if (tid == 0) {
#pragma unroll
      for (int ww = 1; ww < 4; ++ww)
        if (rbv[ww] > bv || (rbv[ww] == bv && rbi[ww] < bi)) { bv = rbv[ww]; bi = rbi[ww]; }
      idxb[n] = bi;
    }
  }
}

// ---------------------------------------------------------------------------
// rescue (fallback, no cbT space)
// ---------------------------------------------------------------------------
__global__ __launch_bounds__(256) void rescue_k(const float* __restrict__ z,
                                                const float* __restrict__ cb,
                                                const float* __restrict__ zin,
                                                const float* __restrict__ ein,
                                                const int* __restrict__ rcount,
                                                const int* __restrict__ rlist,
                                                int* __restrict__ idxb) {
  __shared__ float rbv[4];
  __shared__ int   rbi[4];
  int tid = threadIdx.x, wv = tid >> 6, l = tid & 63;
  int half = l >> 5, ld = l & 31;
  int cnt = *rcount;
  for (int ri = blockIdx.x; ri < cnt; ri += gridDim.x) {
    int n = rlist[ri];
    __syncthreads();
    float rnz = zin[n];
    float4 zv = reinterpret_cast<const float4*>(z + (size_t)n * DDIM)[ld];
    zv.x *= rnz; zv.y *= rnz; zv.z *= rnz; zv.w *= rnz;
    float bv = -3e38f;
    int   bi = 0;
    for (int c0 = wv * 2; c0 < KCB; c0 += 8) {
      int c = c0 + half;
      float4 ev = reinterpret_cast<const float4*>(cb + (size_t)c * DDIM)[ld];
      float p = zv.x * ev.x;
      p = fmaf(zv.y, ev.y, p);
      p = fmaf(zv.z, ev.z, p);
      p = fmaf(zv.w, ev.w, p);
#pragma unroll
      for (int m = 1; m < 32; m <<= 1) p += __shfl_xor(p, m);
      float s = p * ein[c];
      if (s > bv) { bv = s; bi = c; }
    }
#pragma unroll
    for (int m = 1; m < 64; m <<= 1) {
      float ov = __shfl_xor(bv, m);
      int   oi = __shfl_xor(bi, m);
      if (ov > bv || (ov == bv && oi < bi)) { bv = ov; bi = oi; }
    }
    if (l == 0) { rbv[wv] = bv; rbi[wv] = bi; }
    __syncthreads();
    if (tid == 0) {
#pragma unroll
      for (int ww = 1; ww < 4; ++ww)
        if (rbv[ww] > bv || (rbv[ww] == bv && rbi[ww] < bi)) { bv = rbv[ww]; bi = rbi[ww]; }
      idxb[n] = bi;
    }
  }
}

// ---------------------------------------------------------------------------
// counts from final idx
// ---------------------------------------------------------------------------
__global__ __launch_bounds__(256) void count_k(const int* __restrict__ idxb,
                                               int* __restrict__ counts) {
  int n = blockIdx.x * 256 + threadIdx.x;
  atomicAdd(&counts[idxb[n]], 1);
}

// ---------------------------------------------------------------------------
// pass 2 (MFMA f16-hi): recompute scores, accumulate softmax column sums.
// lse arrives in log2 domain -> single exp2 per score.
// ---------------------------------------------------------------------------
__global__ __launch_bounds__(256) void pass2m(const _Float16* __restrict__ znh,
                                              const _Float16* __restrict__ enh,
                                              const float* __restrict__ lse,
                                              float* __restrict__ Ppart) {
  __shared__ _Float16 zt[128 * 128];   // 32 KB
  __shared__ _Float16 et[64 * 128];    // 16 KB
  __shared__ float colbuf[4][64];
  int tid = threadIdx.x;
  int kb = blockIdx.x, nb = blockIdx.y;
  int n0 = nb * 128, k0 = kb * 64;

#pragma unroll
  for (int p = 0; p < 8; ++p) {
    int idx = p * 256 + tid;
    int ch = idx & 15, r = idx >> 4;
    uint4 v = *reinterpret_cast<const uint4*>(znh + (size_t)(n0 + r) * DDIM + ch * 8);
    *reinterpret_cast<uint4*>(&zt[r * 128 + (ch ^ (r & 7)) * 8]) = v;
  }
#pragma unroll
  for (int p = 0; p < 4; ++p) {
    int idx = p * 256 + tid;
    int ch = idx & 15, r = idx >> 4;
    uint4 v = *reinterpret_cast<const uint4*>(enh + (size_t)(k0 + r) * DDIM + ch * 8);
    *reinterpret_cast<uint4*>(&et[r * 128 + (ch ^ (r & 7)) * 8]) = v;
  }
  __syncthreads();

  int wv = tid >> 6, l = tid & 63, lr = l & 15, lk = l >> 4;

  float lse8[2][4];
#pragma unroll
  for (int tr = 0; tr < 2; ++tr)
#pragma unroll
    for (int rg = 0; rg < 4; ++rg)
      lse8[tr][rg] = lse[n0 + wv * 32 + tr * 16 + lk * 4 + rg];

  f16x8 afr[2][4];
#pragma unroll
  for (int tr = 0; tr < 2; ++tr) {
    int row = wv * 32 + tr * 16 + lr;
#pragma unroll
    for (int dc = 0; dc < 4; ++dc)
      afr[tr][dc] = *reinterpret_cast<const f16x8*>(
          &zt[row * 128 + ((4 * dc + lk) ^ (row & 7)) * 8]);
  }

#pragma unroll
  for (int ct = 0; ct < 4; ++ct) {
    f32x4 acc0 = {0.f, 0.f, 0.f, 0.f};
    f32x4 acc1 = {0.f, 0.f, 0.f, 0.f};
    int col = ct * 16 + lr;
#pragma unroll
    for (int dc = 0; dc < 4; ++dc) {
      f16x8 bfr = *reinterpret_cast<const f16x8*>(
          &et[col * 128 + ((4 * dc + lk) ^ (col & 7)) * 8]);
      acc0 = __builtin_amdgcn_mfma_f32_16x16x32_f16(afr[0][dc], bfr, acc0, 0, 0, 0);
      acc1 = __builtin_amdgcn_mfma_f32_16x16x32_f16(afr[1][dc], bfr, acc1, 0, 0, 0);
    }
    float pc = 0.0f;
#pragma unroll
    for (int rg = 0; rg < 4; ++rg) {
      pc += exp2f(fmaf(acc0[rg], S12, -lse8[0][rg]));
      pc += exp2f(fmaf(acc1[rg], S12, -lse8[1][rg]));
    }
    pc += __shfl_xor(pc, 16);
    pc += __shfl_xor(pc, 32);
    if (l < 16) colbuf[wv][ct * 16 + l] = pc;
  }
  __syncthreads();
  if (tid < 64)
    Ppart[(size_t)nb * KCB + k0 + tid] =
        colbuf[0][tid] + colbuf[1][tid] + colbuf[2][tid] + colbuf[3][tid];
}

// ---------------------------------------------------------------------------
// gather z_q, emit z_q_ste = z + (z_q - z), block-partial commit sums
// ---------------------------------------------------------------------------
__global__ __launch_bounds__(256) void k3(const float* __restrict__ z,
                                          const float* __restrict__ cb,
                                          const int* __restrict__ idxb,
                                          float* __restrict__ out,
                                          float* __restrict__ cpart) {
  int tid = threadIdx.x;
  int e   = blockIdx.x * 256 + tid;
  int n   = e >> 5;
  int q   = e & 31;
  int id  = idxb[n];
  float4 c4 = reinterpret_cast<const float4*>(cb)[id * 32 + q];
  float4 z4 = reinterpret_cast<const float4*>(z)[e];
  float4 o;
  o.x = z4.x + (c4.x - z4.x);
  o.y = z4.y + (c4.y - z4.y);
  o.z = z4.z + (c4.z - z4.z);
  o.w = z4.w + (c4.w - z4.w);
  reinterpret_cast<float4*>(out)[e] = o;
  float dx = c4.x - z4.x, dy = c4.y - z4.y, dz = c4.z - z4.z, dw = c4.w - z4.w;
  float ds = dx * dx + dy * dy + dz * dz + dw * dw;
#pragma unroll
  for (int m = 1; m < 64; m <<= 1) ds += __shfl_xor(ds, m);
  __shared__ float wsum[4];
  if ((tid & 63) == 0) wsum[tid >> 6] = ds;
  __syncthreads();
  if (tid == 0) cpart[blockIdx.x] = wsum[0] + wsum[1] + wsum[2] + wsum[3];
}

// ---------------------------------------------------------------------------
// reduce Ppart[rows][K] -> Psum[K]
// ---------------------------------------------------------------------------
__global__ __launch_bounds__(256) void reduceP(const float* __restrict__ Ppart,
                                               float* __restrict__ Psum,
                                               int rows) {
  int k = blockIdx.x * 256 + threadIdx.x;
  float s = 0.0f;
  for (int b = 0; b < rows; ++b) s += Ppart[(size_t)b * KCB + k];
  Psum[k] = s;
}

// ---------------------------------------------------------------------------
// final scalars: commit, perplexity, entropy_loss, min(ema)
// ---------------------------------------------------------------------------
__global__ __launch_bounds__(256) void finalk(const int* __restrict__ counts,
                                              const float* __restrict__ Psum,
                                              const float* __restrict__ pema,
                                              const float* __restrict__ cpart,
                                              float* __restrict__ out) {
  int tid = threadIdx.x;
  float s1 = 0.0f, s2 = 0.0f, cs = 0.0f, mn = 1e30f;
  const float invN = 1.0f / (float)NTOK;
  const float thr  = 0.0125f / (float)KCB;
  const float invK = 1.0f / (float)KCB;
  for (int k = tid; k < KCB; k += 256) {
    float e = (float)counts[k] * invN;
    s1 += e * logf(e + 1e-8f);
    float pa = Psum[k] * invN + 1e-8f;
    s2 += pa * logf(pa);
    float ema  = 0.9f * pema[k] + 0.1f * e;
    float emaf = (ema < thr) ? invK : ema;
    mn = fminf(mn, emaf);
  }
  for (int b = tid; b < 2048; b += 256) cs += cpart[b];
#pragma unroll
  for (int m = 1; m < 64; m <<= 1) {
    s1 += __shfl_xor(s1, m);
    s2 += __shfl_xor(s2, m);
    cs += __shfl_xor(cs, m);
    mn = fminf(mn, __shfl_xor(mn, m));
  }
  __shared__ float r1[4], r2[4], r3[4], r4[4];
  if ((tid & 63) == 0) {
    int w = tid >> 6;
    r1[w] = s1; r2[w] = s2; r3[w] = cs; r4[w] = mn;
  }
  __syncthreads();
  if (tid == 0) {
    float S1 = r1[0] + r1[1] + r1[2] + r1[3];
    float S2 = r2[0] + r2[1] + r2[2] + r2[3];
    float CS = r3[0] + r3[1] + r3[2] + r3[3];
    float MN = fminf(fminf(r4[0], r4[1]), fminf(r4[2], r4[3]));
    out[OUT_MAIN + 0] = 1.25f * CS / (float)OUT_MAIN;
    out[OUT_MAIN + 1] = expf(-S1);
    out[OUT_MAIN + 2] = -S2;
    out[OUT_MAIN + 3] = MN;
  }
}

// ---------------------------------------------------------------------------
extern "C" void kernel_launch(void* const* d_in, const int* in_sizes, int n_in,
                              void* d_out, int out_size, void* d_ws, size_t ws_size,
                              hipStream_t stream) {
  const float* z    = (const float*)d_in[0];
  const float* cb   = (const float*)d_in[1];
  const float* pema = (const float*)d_in[2];
  float* out = (float*)d_out;
  char*  ws  = (char*)d_ws;

  // workspace layout (25 MB with cbT; 21 MB without)
  _Float16* znh = (_Float16*)(ws + 0x000000);            // 4 MB
  _Float16* znl = (_Float16*)(ws + 0x400000);            // 4 MB
  _Float16* enh = (_Float16*)(ws + 0x800000);            // 2 MB
  _Float16* enl = (_Float16*)(ws + 0xA00000);            // 2 MB
  char* sb = ws + 0xC00000;
  float* zin    = (float*)(sb + 0x00000);                // 64 KB
  float* ein    = (float*)(sb + 0x10000);                // 32 KB
  float* lse    = (float*)(sb + 0x18000);                // 64 KB
  int*   idxb   = (int*)  (sb + 0x28000);                // 64 KB
  int*   counts = (int*)  (sb + 0x38000);                // 32 KB
  int*   rcount = (int*)  (sb + 0x40000);                // 4 B (+pad)
  int*   rlist  = (int*)  (sb + 0x41000);                // 64 KB
  float* Psum   = (float*)(sb + 0x51000);                // 32 KB
  float* cpart  = (float*)(sb + 0x59000);                // 8 KB
  char* pb = ws + 0xD00000;                              // partials: 8 MB
  float* pb1  = (float*)(pb + 0x000000);
  int*   pidx = (int*)  (pb + 0x200000);
  float* pb2  = (float*)(pb + 0x400000);
  float* pL   = (float*)(pb + 0x600000);
  float* Ppart = (float*)(ws + 0xD00000);                // 4 MB alias (after merge2)
  float* cbT   = (float*)(ws + 0x1500000);               // 4 MB (optional)

  bool havecbt = ws_size >= (size_t)0x1900000;

  hipMemsetAsync(counts, 0, KCB * sizeof(int) + 0x400, stream);  // counts + rcount

  norm_k <<<(NTOK + KCB) / 4, 256, 0, stream>>>(z, cb, znh, znl, enh, enl, zin, ein);
  if (havecbt)
    transp_k<<<dim3(KCB / 64, DDIM / 32), 256, 0, stream>>>(cb, cbT);
  pass1m <<<dim3(32, 32),     256, 0, stream>>>(znh, znl, enh, enl, pb1, pidx, pb2, pL);
  merge2_k<<<NTOK / 256,      256, 0, stream>>>(pb1, pidx, pb2, pL, lse, idxb, rcount, rlist);
  if (havecbt)
    rescue2_k<<<2048,         256, 0, stream>>>(z, cbT, zin, ein, rcount, rlist, idxb);
  else
    rescue_k<<<1024,          256, 0, stream>>>(z, cb, zin, ein, rcount, rlist, idxb);
  count_k<<<NTOK / 256,       256, 0, stream>>>(idxb, counts);
  pass2m <<<dim3(KCB / 64, NTOK / 128), 256, 0, stream>>>(znh, enh, lse, Ppart);
  k3     <<<NTOK * DDIM / 4 / 256, 256, 0, stream>>>(z, cb, idxb, out, cpart);
  reduceP<<<KCB / 256,        256, 0, stream>>>(Ppart, Psum, NTOK / 128);
  finalk <<<1,                256, 0, stream>>>(counts, Psum, pema, cpart, out);
}